// Round 6
// baseline (28.475 us; speedup 1.0000x reference)
//
#include <hip/hip_runtime.h>
#include <stdint.h>

#define CN 144
#define VN 576
#define BN 1024
#define NITER 3
#define RCAP 40      // row-weight capacity, multiple of 4 (actual max ~28)
#define NQ   (RCAP/4)
#define CCAP 8       // column-weight capacity (actual 4)
#define TPB 192      // 3 waves; 576/192 = exactly 3 columns per thread

// ws layout (ints):
#define WS_RLEN 0                  // [0,144)  row lengths (by check c)
#define WS_CTR  144                // election counter (works from any initial value)
#define WS_CCOF 160                // [160,304)  c -> rank (sorted by rl, stable)
#define WS_RLR  304                // [304,448)  rank -> clamped rl
#define WS_CCNT 448                // [448,1024) per-column edge count
#define WS_LOC  1024               // [+CN*VN)   loc[v*CN+c] = slot in row, -1 if none
#define WS_CSC2 (1024 + CN*VN)     // [+VN*4)    int4 per column: edge ids j=0..3
#define WS_CSX  (WS_CSC2 + VN*4)   // [+VN*4)    edge ids j=4..7 (rare)

// edge id for (row-slot l, check-rank cc), quad layout:
// float index ((l>>2)*CN + cc)*4 + (l&3) -> lane-consecutive float4 per (l>>2, cc)
__device__ __forceinline__ int edge_id(int l, int cc) {
    return (((l >> 2) * CN + cc) << 2) | (l & 3);
}

// ---- build 1: per-row ballot compaction; last-done block computes rank perm ----
__global__ __launch_bounds__(192) void build_stage(const float* __restrict__ H,
                                                   int* __restrict__ ws) {
    __shared__ int rls[CN];
    __shared__ int hist[RCAP + 1];
    __shared__ int pfx[RCAP + 1];
    __shared__ int iswin;
    const int c = blockIdx.x;          // 144 blocks
    const int t = threadIdx.x;

    if (t < 64) {                      // wave 0: row compaction
        int base = 0;
        const float* row = H + c * VN;
        for (int ch = 0; ch < VN / 64; ++ch) {
            const int v = ch * 64 + t;
            const bool set = row[v] > 0.5f;
            const unsigned long long mask = __ballot(set);
            const int off = base + (int)__popcll(mask & ((1ULL << t) - 1ULL));
            ws[WS_LOC + v * CN + c] = set ? off : -1;   // ascending-v slot order
            base += (int)__popcll(mask);
        }
        if (t == 0) ws[WS_RLEN + c] = base;
    }
    // last-done election: exactly one of the 144 adds satisfies old%144==143,
    // regardless of the counter's (possibly poisoned) initial value.
    if (t == 0) {
        __threadfence();
        const unsigned old = atomicAdd((unsigned*)(ws + WS_CTR), 1u);
        iswin = ((old % (unsigned)CN) == (unsigned)(CN - 1)) ? 1 : 0;
    }
    __syncthreads();
    if (!iswin) return;
    __threadfence();

    // stable counting sort of checks by clamped rl (ties by c) -> rank
    if (t < CN)
        rls[t] = min(__hip_atomic_load(ws + WS_RLEN + t, __ATOMIC_RELAXED,
                                       __HIP_MEMORY_SCOPE_AGENT), RCAP);
    if (t <= RCAP) hist[t] = 0;
    __syncthreads();
    if (t < CN) atomicAdd(&hist[rls[t]], 1);
    __syncthreads();
    if (t == 0) {
        int acc = 0;
        for (int i = 0; i <= RCAP; ++i) { pfx[i] = acc; acc += hist[i]; }
    }
    __syncthreads();
    if (t < CN) {
        const int key = rls[t];
        int tie = 0;
        for (int c2 = 0; c2 < t; ++c2) tie += (rls[c2] == key) ? 1 : 0;
        const int cc = pfx[key] + tie;
        ws[WS_CCOF + t] = cc;
        ws[WS_RLR + cc] = key;
    }
}

// ---- build 2: one wave per column; ballot compaction into int4 CSC (rank ids) ----
__global__ __launch_bounds__(64) void build_csc(int* __restrict__ ws) {
    const int v = blockIdx.x;          // 576 blocks
    const int lane = threadIdx.x;      // 64
    int cnt = 0;
    for (int ch = 0; ch < 3; ++ch) {
        const int c = ch * 64 + lane;
        const int l = (c < CN) ? ws[WS_LOC + v * CN + c] : -1;   // coalesced
        const bool set = (l >= 0) && (l < RCAP);
        const unsigned long long mask = __ballot(set);
        const int off = cnt + (int)__popcll(mask & ((1ULL << lane) - 1ULL));
        if (set && off < CCAP) {
            const int cc = ws[WS_CCOF + c];
            const int e = edge_id(l, cc);
            if (off < 4) ws[WS_CSC2 + v * 4 + off] = e;
            else         ws[WS_CSX  + v * 4 + (off - 4)] = e;
        }
        cnt += (int)__popcll(mask);
    }
    if (cnt > CCAP) cnt = CCAP;
    if (lane == 0) ws[WS_CCNT + v] = cnt;
    if (lane < 4 && lane >= cnt)     ws[WS_CSC2 + v * 4 + lane] = 0;   // defined, unused
    if (lane < 4 && lane + 4 >= cnt) ws[WS_CSX  + v * 4 + lane] = 0;
}

// ---- decode: one block per batch item ----
__global__ __launch_bounds__(TPB) void ldpc_decode(const float* __restrict__ r,
                                                   const float* __restrict__ alpha,
                                                   const int* __restrict__ ws,
                                                   float* __restrict__ out) {
    __shared__ float4 M4[NQ * CN];
    float* const Mf = reinterpret_cast<float*>(M4);

    const int b = blockIdx.x;
    const int t = threadIdx.x;
    const float a_[NITER] = { alpha[0], alpha[1], alpha[2] };

    // per-thread columns v = t + q*TPB
    int   ent4[3][4], entX[3][4];
    int   cnt[3];
    float rv[3];
    #pragma unroll
    for (int q = 0; q < 3; ++q) {
        const int v = t + q * TPB;
        rv[q]  = r[b * VN + v];
        cnt[q] = ws[WS_CCNT + v];
        const int4 e4 = *reinterpret_cast<const int4*>(ws + WS_CSC2 + v * 4);
        ent4[q][0] = e4.x; ent4[q][1] = e4.y; ent4[q][2] = e4.z; ent4[q][3] = e4.w;
    }
    const int rl = (t < CN) ? ws[WS_RLR + t] : 0;   // row length by rank
    const int any_hi = __syncthreads_or((cnt[0] > 4) | (cnt[1] > 4) | (cnt[2] > 4));
    if (any_hi) {
        #pragma unroll
        for (int q = 0; q < 3; ++q) {
            const int4 e4 = *reinterpret_cast<const int4*>(ws + WS_CSX + (t + q * TPB) * 4);
            entX[q][0] = e4.x; entX[q][1] = e4.y; entX[q][2] = e4.z; entX[q][3] = e4.w;
        }
    }

    // INF pads up to quad boundary (preserved across iterations)
    if (t < CN) {
        const int rpad = (rl + 3) & ~3;
        for (int k = rl; k < rpad; ++k) Mf[edge_id(k, t)] = INFINITY;
    }
    // M init = r on real edges (disjoint from pads)
    #pragma unroll
    for (int q = 0; q < 3; ++q) {
        #pragma unroll
        for (int j = 0; j < 4; ++j) if (j < cnt[q]) Mf[ent4[q][j]] = rv[q];
    }
    if (any_hi) {
        #pragma unroll
        for (int q = 0; q < 3; ++q) {
            #pragma unroll
            for (int j = 0; j < 4; ++j) if (4 + j < cnt[q]) Mf[entX[q][j]] = rv[q];
        }
    }
    __syncthreads();

    #pragma unroll
    for (int it = 0; it < NITER; ++it) {
        const float a = a_[it];

        // Pass A: register-cached quads; min1/min2/first-argmin/sign; E in place.
        if (t < CN) {
            const int nq = (rl + 3) >> 2;
            float4 mv[NQ];                           // statically indexed (unrolled)
            uint32_t m1 = 0x7fffffffu, m2 = 0x7fffffffu, sg = 0u;
            int am = 0;
            #pragma unroll
            for (int q4 = 0; q4 < NQ; ++q4) {
                if (q4 < nq) {
                    mv[q4] = M4[q4 * CN + t];
                    const float* mp = reinterpret_cast<const float*>(&mv[q4]);
                    #pragma unroll
                    for (int j = 0; j < 4; ++j) {
                        const uint32_t mb = __float_as_uint(mp[j]);
                        const uint32_t ab = mb & 0x7fffffffu;   // INF pads never win
                        sg ^= mb;
                        const bool lt = ab < m1;                // strict: first occurrence
                        m2 = lt ? m1 : ((ab < m2) ? ab : m2);
                        m1 = lt ? ab : m1;
                        am = lt ? (q4 * 4 + j) : am;
                    }
                }
            }
            sg &= 0x80000000u;                                  // pads are +INF: sign +1
            const uint32_t p1b = __float_as_uint(a * __uint_as_float(m1)) ^ sg;
            const uint32_t p2b = __float_as_uint(a * __uint_as_float(m2)) ^ sg;
            #pragma unroll
            for (int q4 = 0; q4 < NQ; ++q4) {
                if (q4 < nq) {
                    const float* mp = reinterpret_cast<const float*>(&mv[q4]);
                    float4 ev;
                    float* ep = reinterpret_cast<float*>(&ev);
                    #pragma unroll
                    for (int j = 0; j < 4; ++j) {
                        const int k = q4 * 4 + j;
                        const uint32_t mb = __float_as_uint(mp[j]);
                        const uint32_t ps = (k == am) ? p2b : p1b;
                        ep[j] = (k < rl) ? __uint_as_float(ps ^ (mb & 0x80000000u))
                                         : mp[j];               // preserve INF pads
                    }
                    M4[q4 * CN + t] = ev;
                }
            }
        }
        __syncthreads();

        // Pass B: per-column gather of E (ascending-c order), col-sum, fused M update
        #pragma unroll
        for (int q = 0; q < 3; ++q) {
            float E4[4], EX[4];
            float col = 0.0f;
            #pragma unroll
            for (int j = 0; j < 4; ++j) {
                E4[j] = (j < cnt[q]) ? Mf[ent4[q][j]] : 0.0f;
                col += E4[j];
            }
            if (any_hi) {
                #pragma unroll
                for (int j = 0; j < 4; ++j) {
                    EX[j] = (4 + j < cnt[q]) ? Mf[entX[q][j]] : 0.0f;
                    col += EX[j];
                }
            }
            if (it == NITER - 1) {
                out[b * VN + t + q * TPB] = rv[q] + col;
            } else {
                const float mb = col + rv[q];
                #pragma unroll
                for (int j = 0; j < 4; ++j) if (j < cnt[q]) Mf[ent4[q][j]] = mb - E4[j];
                if (any_hi) {
                    #pragma unroll
                    for (int j = 0; j < 4; ++j) if (4 + j < cnt[q]) Mf[entX[q][j]] = mb - EX[j];
                }
            }
        }
        if (it < NITER - 1) __syncthreads();
    }
}

extern "C" void kernel_launch(void* const* d_in, const int* in_sizes, int n_in,
                              void* d_out, int out_size, void* d_ws, size_t ws_size,
                              hipStream_t stream) {
    const float* r     = (const float*)d_in[0];
    const float* alpha = (const float*)d_in[1];
    const float* H     = (const float*)d_in[2];
    float* out = (float*)d_out;
    int* ws    = (int*)d_ws;

    build_stage<<<CN, 192, 0, stream>>>(H, ws);
    build_csc<<<VN, 64, 0, stream>>>(ws);
    ldpc_decode<<<BN, TPB, 0, stream>>>(r, alpha, ws, out);
}